// Round 1
// baseline (1026.341 us; speedup 1.0000x reference)
//
#include <hip/hip_runtime.h>
#include <stdint.h>

typedef unsigned long long u64;
typedef int v8i  __attribute__((ext_vector_type(8)));
typedef float v16f __attribute__((ext_vector_type(16)));

#define BATCH 16384
#define IND   768
#define HID   4096
#define NOUT  10
#define EPS   1e-5f

// ---------------------------------------------------------------------------
// Pack sign bits row-major: dst[row][w]. Used for W4 only (final layer).
// ---------------------------------------------------------------------------
__global__ void pack_sign_kernel(const float* __restrict__ src, int ld, int nwords,
                                 int nrows, u64* __restrict__ dst) {
    int gt   = blockIdx.x * blockDim.x + threadIdx.x;
    int wave = gt >> 6;
    int lane = gt & 63;
    if (wave >= nrows) return;
    const float* row = src + (size_t)wave * ld;
    u64* drow = dst + (size_t)wave * nwords;
    for (int w = 0; w < nwords; ++w) {
        float v = row[(w << 6) + lane];
        u64 m = __ballot(v < 0.0f);
        if (lane == 0) drow[w] = m;
    }
}

// ---------------------------------------------------------------------------
// Pack sign bits TRANSPOSED: dst[w][row]. One block per row, 4 waves split
// the word range.
// ---------------------------------------------------------------------------
__global__ void pack_sign_t_kernel(const float* __restrict__ src, int ld,
                                   int nwords, int nrows, u64* __restrict__ dst) {
    int row  = blockIdx.x;
    int wave = threadIdx.x >> 6, lane = threadIdx.x & 63;
    int nw4  = (nwords + 3) >> 2;
    int wend = (wave + 1) * nw4; if (wend > nwords) wend = nwords;
    const float* r = src + (size_t)row * ld;
    for (int w = wave * nw4; w < wend; ++w) {
        u64 m = __ballot(r[(w << 6) + lane] < 0.0f);
        if (lane == 0) dst[(size_t)w * nrows + row] = m;
    }
}

// ---------------------------------------------------------------------------
// 32 bits -> 4 dwords of fp4(e2m1) nibbles: nibble j = +1 (0x2) or -1 (0xA)
// per bit j (bit set == negative, matching the sign-bit packing).
// Per dword k (bits 8k..8k+7):
//   even bits i in {0,2,4,6} -> nibble-bit 4i+3 via magic 0x00208208
//   odd  bits i in {1,3,5,7} -> nibble-bit 4i+3 via magic 0x01041040
// (collision/carry checked: masked positions receive exactly one term,
//  carries never propagate into a masked position)
// Writes only elements [0:3] of the v8i (fp4 MFMA reads 4 regs).
// ---------------------------------------------------------------------------
__device__ __forceinline__ void expand_fp4(unsigned w, v8i& f) {
    #pragma unroll
    for (int k = 0; k < 4; ++k) {
        unsigned b = w >> (8 * k);
        unsigned e = ((b & 0x55u) * 0x00208208u) & 0x08080808u;
        unsigned o = ((b & 0xAAu) * 0x01041040u) & 0x80808080u;
        f[k] = (int)(0x22222222u | e | o);
    }
}

// ---------------------------------------------------------------------------
// Binarized GEMM via MX-FP4 MFMA (scale = 1.0): bit-words loaded straight
// from L2-resident bit planes, expanded in-register to +/-1 fp4 nibbles,
// mfma_scale_f32_32x32x64_f8f6f4 accumulates the EXACT signed dot in f32
// (|dot| <= 4096 < 2^24). No popcount correction, no LDS, no barriers.
// Block tile 256x256, 4 waves, wave tile 128x128 (4x4 of 32x32), K-step 64.
// 1-round-ahead register prefetch covers L2 latency at 1 wave/SIMD.
// ---------------------------------------------------------------------------
__global__ __launch_bounds__(256, 1) void bgemm_fp4(
    const u64* __restrict__ AT,   // [rounds][BATCH] bit planes
    int rounds,
    const u64* __restrict__ WT,   // [rounds][HID] bit planes
    const float* __restrict__ bias, const float* __restrict__ gam,
    const float* __restrict__ bet,  const float* __restrict__ mu,
    const float* __restrict__ var,
    u64* __restrict__ OT,         // [64][BATCH] bit planes
    u64* __restrict__ ORM)        // [BATCH][64] row-major or nullptr
{
    const int tid = threadIdx.x;
    const int bm  = blockIdx.x >> 4;        // 16 consecutive blocks share A panel
    const int bn  = blockIdx.x & 15;
    const int m0  = bm << 8, n0 = bn << 8;

    const int wave = tid >> 6, lane = tid & 63;
    const int mh = (wave & 1) << 7, nh = (wave >> 1) << 7;
    const int l31 = lane & 31, q = lane >> 5;

    v16f acc[4][4];
    #pragma unroll
    for (int a = 0; a < 4; ++a)
        #pragma unroll
        for (int b = 0; b < 4; ++b)
            #pragma unroll
            for (int k = 0; k < 16; ++k) acc[a][b][k] = 0.0f;

    // lane (l31, q): row/col = base + 32*t + l31, K-half q -> dword q of u64
    const char* Ap = (const char*)AT + (((size_t)(m0 + mh + l31)) << 3) + (q << 2);
    const char* Bp = (const char*)WT + (((size_t)(n0 + nh + l31)) << 3) + (q << 2);
    const size_t Astep = (size_t)BATCH << 3;
    const size_t Bstep = (size_t)HID << 3;

    unsigned wa[4], wb[4];
    #pragma unroll
    for (int t = 0; t < 4; ++t) {
        wa[t] = *(const unsigned*)(Ap + 256 * t);   // 32 rows * 8B = 256B imm offset
        wb[t] = *(const unsigned*)(Bp + 256 * t);
    }

    const int sc1 = 0x7f7f7f7f;                     // e8m0 127 -> 2^0 scales
    v8i zf = {0, 0, 0, 0, 0, 0, 0, 0};
    v8i bf[4] = {zf, zf, zf, zf};
    v8i af = zf;

    for (int c = 0; c < rounds; ++c) {
        // prefetch next round's bit words (re-loads current on last round)
        if (c + 1 < rounds) { Ap += Astep; Bp += Bstep; }
        unsigned na[4], nb[4];
        #pragma unroll
        for (int t = 0; t < 4; ++t) {
            na[t] = *(const unsigned*)(Ap + 256 * t);
            nb[t] = *(const unsigned*)(Bp + 256 * t);
        }

        #pragma unroll
        for (int tj = 0; tj < 4; ++tj) expand_fp4(wb[tj], bf[tj]);

        #pragma unroll
        for (int ti = 0; ti < 4; ++ti) {
            expand_fp4(wa[ti], af);
            #pragma unroll
            for (int tj = 0; tj < 4; ++tj)
                acc[ti][tj] = __builtin_amdgcn_mfma_scale_f32_32x32x64_f8f6f4(
                    af, bf[tj], acc[ti][tj], 4, 4, 0, sc1, 0, sc1);
        }

        #pragma unroll
        for (int t = 0; t < 4; ++t) { wa[t] = na[t]; wb[t] = nb[t]; }
    }

    // epilogue: exact dot already in acc (f32 integer), BN, ballot sign-pack
    float scj[4], muj[4], bej[4], bij[4];
    #pragma unroll
    for (int tj = 0; tj < 4; ++tj) {
        int col = n0 + nh + 32 * tj + l31;
        scj[tj] = gam[col] * rsqrtf(var[col] + EPS);
        muj[tj] = mu[col]; bej[tj] = bet[col]; bij[tj] = bias[col];
    }
    const int pn0 = (n0 + nh) >> 6;                 // first output bit-plane
    u64* out0 = OT + (size_t)pn0 * BATCH;
    u64* out1 = OT + (size_t)(pn0 + 1) * BATCH;

    #pragma unroll
    for (int ti = 0; ti < 4; ++ti) {
        #pragma unroll
        for (int reg = 0; reg < 16; ++reg) {
            int rbase = (reg & 3) + 8 * (reg >> 2);
            u64 bl[4];
            #pragma unroll
            for (int tj = 0; tj < 4; ++tj) {
                float h = acc[ti][tj][reg] + bij[tj];
                float y = (h - muj[tj]) * scj[tj] + bej[tj];
                bl[tj] = __ballot(y < 0.0f);
            }
            int rA = m0 + mh + 32 * ti + rbase;     // q=0 lanes' row
            u64 w0A = (bl[0] & 0xFFFFFFFFull) | (bl[1] << 32);
            u64 w0B = (bl[0] >> 32) | (bl[1] & 0xFFFFFFFF00000000ull);
            u64 w1A = (bl[2] & 0xFFFFFFFFull) | (bl[3] << 32);
            u64 w1B = (bl[2] >> 32) | (bl[3] & 0xFFFFFFFF00000000ull);
            if (lane == 0) {
                out0[rA] = w0A; out1[rA] = w1A;
                if (ORM) {
                    ORM[(size_t)rA * 64 + pn0]     = w0A;
                    ORM[(size_t)rA * 64 + pn0 + 1] = w1A;
                }
            } else if (lane == 32) {
                out0[rA + 4] = w0B; out1[rA + 4] = w1B;
                if (ORM) {
                    ORM[(size_t)(rA + 4) * 64 + pn0]     = w0B;
                    ORM[(size_t)(rA + 4) * 64 + pn0 + 1] = w1B;
                }
            }
        }
    }
}

// ---------------------------------------------------------------------------
// Final layer: N=10, K=4096 (64 words). One wave per row; exact-int dots,
// BN, log_softmax.
// ---------------------------------------------------------------------------
__global__ void final_layer_kernel(
    const u64* __restrict__ Ap,   // [B][64] row-major
    const u64* __restrict__ Wp,   // [10][64] row-major
    const float* __restrict__ bias, const float* __restrict__ gam,
    const float* __restrict__ bet,  const float* __restrict__ mu,
    const float* __restrict__ var,
    float* __restrict__ out)      // [B][10]
{
    int gt   = blockIdx.x * blockDim.x + threadIdx.x;
    int row  = gt >> 6;
    int lane = gt & 63;
    if (row >= BATCH) return;

    u64 a = Ap[(size_t)row * 64 + lane];
    unsigned p[NOUT];
    #pragma unroll
    for (int j = 0; j < NOUT; ++j)
        p[j] = (unsigned)__popcll(a ^ Wp[j * 64 + lane]);

    #pragma unroll
    for (int j = 0; j < NOUT; ++j) {
        #pragma unroll
        for (int off = 32; off >= 1; off >>= 1)
            p[j] += __shfl_xor(p[j], off, 64);
    }

    float z[NOUT];
    float mx = -1e30f;
    #pragma unroll
    for (int j = 0; j < NOUT; ++j) {
        float hh = (float)(HID - 2 * (int)p[j]) + bias[j];
        float sc = gam[j] * rsqrtf(var[j] + EPS);
        z[j] = (hh - mu[j]) * sc + bet[j];
        mx = fmaxf(mx, z[j]);
    }
    float s = 0.0f;
    #pragma unroll
    for (int j = 0; j < NOUT; ++j) s += expf(z[j] - mx);
    float lse = logf(s) + mx;
    if (lane < NOUT) out[(size_t)row * NOUT + lane] = z[lane] - lse;
}

// ---------------------------------------------------------------------------
extern "C" void kernel_launch(void* const* d_in, const int* in_sizes, int n_in,
                              void* d_out, int out_size, void* d_ws, size_t ws_size,
                              hipStream_t stream) {
    (void)in_sizes; (void)n_in; (void)out_size; (void)ws_size;

    const float* x   = (const float*)d_in[0];
    const float* w1  = (const float*)d_in[1];
    const float* b1  = (const float*)d_in[2];
    const float* g1  = (const float*)d_in[3];
    const float* be1 = (const float*)d_in[4];
    const float* m1  = (const float*)d_in[5];
    const float* v1  = (const float*)d_in[6];
    const float* w2  = (const float*)d_in[7];
    const float* b2  = (const float*)d_in[8];
    const float* g2  = (const float*)d_in[9];
    const float* be2 = (const float*)d_in[10];
    const float* m2  = (const float*)d_in[11];
    const float* v2  = (const float*)d_in[12];
    const float* w3  = (const float*)d_in[13];
    const float* b3  = (const float*)d_in[14];
    const float* g3  = (const float*)d_in[15];
    const float* be3 = (const float*)d_in[16];
    const float* m3  = (const float*)d_in[17];
    const float* v3  = (const float*)d_in[18];
    const float* w4  = (const float*)d_in[19];
    const float* b4  = (const float*)d_in[20];
    const float* g4  = (const float*)d_in[21];
    const float* be4 = (const float*)d_in[22];
    const float* m4  = (const float*)d_in[23];
    const float* v4  = (const float*)d_in[24];

    u64* ws   = (u64*)d_ws;
    u64* xpT  = ws;                              // 12*16384
    u64* w1T  = xpT + (size_t)12 * BATCH;        // 12*4096
    u64* w2T  = w1T + (size_t)12 * HID;          // 64*4096
    u64* w3T  = w2T + (size_t)64 * HID;          // 64*4096
    u64* w4p  = w3T + (size_t)64 * HID;          // 10*64
    u64* a1T  = w4p + (size_t)NOUT * 64;         // 64*16384
    u64* a2T  = a1T + (size_t)64 * BATCH;        // 64*16384
    u64* a3RM = a2T + (size_t)64 * BATCH;        // 16384*64
    u64* a3T  = a1T;                             // reuse (a1 dead in layer 3)

    // pack (transposed bit-planes; w4 row-major for the final kernel)
    pack_sign_t_kernel<<<BATCH, 256, 0, stream>>>(x, 784, 12, BATCH, xpT);
    pack_sign_t_kernel<<<HID, 256, 0, stream>>>(w1, IND, 12, HID, w1T);
    pack_sign_t_kernel<<<HID, 256, 0, stream>>>(w2, HID, 64, HID, w2T);
    pack_sign_t_kernel<<<HID, 256, 0, stream>>>(w3, HID, 64, HID, w3T);
    pack_sign_kernel<<<3, 256, 0, stream>>>(w4, HID, 64, NOUT, w4p);

    // layers 1-3: grid = (16384/256) * (4096/256) = 64*16 = 1024 blocks
    bgemm_fp4<<<1024, 256, 0, stream>>>(xpT, 12, w1T,
                                        b1, g1, be1, m1, v1, a1T, nullptr);
    bgemm_fp4<<<1024, 256, 0, stream>>>(a1T, 64, w2T,
                                        b2, g2, be2, m2, v2, a2T, nullptr);
    bgemm_fp4<<<1024, 256, 0, stream>>>(a2T, 64, w3T,
                                        b3, g3, be3, m3, v3, a3T, a3RM);
    // layer 4 + log_softmax
    final_layer_kernel<<<BATCH / 4, 256, 0, stream>>>(a3RM, w4p,
                                                      b4, g4, be4, m4, v4,
                                                      (float*)d_out);
}

// Round 2
// 710.633 us; speedup vs baseline: 1.4443x; 1.4443x over previous
//
#include <hip/hip_runtime.h>
#include <stdint.h>

typedef unsigned long long u64;
typedef int v4i  __attribute__((ext_vector_type(4)));
typedef int v8i  __attribute__((ext_vector_type(8)));
typedef float v16f __attribute__((ext_vector_type(16)));

#define BATCH 16384
#define IND   768
#define HID   4096
#define NOUT  10
#define EPS   1e-5f

// ---------------------------------------------------------------------------
// 8 sign bits -> dword of 8 fp4(e2m1) nibbles: nibble i = +1 (0x2) if bit i
// clear, -1 (0xA) if set. All full-rate ops (mul operands fit 24 bits).
// Same magic family as the harness-verified R1 expansion.
// ---------------------------------------------------------------------------
__device__ __forceinline__ unsigned nib8(unsigned b) {
    unsigned e = ((b & 0x55u) * 0x00208208u) & 0x08080808u;
    unsigned o = (((b >> 1) & 0x55u) * 0x00208208u) & 0x08080808u;
    return 0x22222222u | e | (o << 4);
}

// ---------------------------------------------------------------------------
// Pack sign bits row-major: dst[row][w]. Used for W4 only (final layer).
// ---------------------------------------------------------------------------
__global__ void pack_sign_kernel(const float* __restrict__ src, int ld, int nwords,
                                 int nrows, u64* __restrict__ dst) {
    int gt   = blockIdx.x * blockDim.x + threadIdx.x;
    int wave = gt >> 6;
    int lane = gt & 63;
    if (wave >= nrows) return;
    const float* row = src + (size_t)wave * ld;
    u64* drow = dst + (size_t)wave * nwords;
    for (int w = 0; w < nwords; ++w) {
        float v = row[(w << 6) + lane];
        u64 m = __ballot(v < 0.0f);
        if (lane == 0) drow[w] = m;
    }
}

// ---------------------------------------------------------------------------
// float -> fp4 nibble planes, transposed for the GEMM fragment layout:
// dst is [2*nwords][nrows] of 16B chunks; chunk (2w+q, row) holds nibbles for
// K = 64w + 32q .. +31 of that row. One block per row; 4 waves split words;
// ballot gives the 64-bit sign word uniform across lanes, lanes 0..7 expand
// and store the 8 output dwords. Memory-bound on the float read.
// ---------------------------------------------------------------------------
__global__ void pack_nib_t_kernel(const float* __restrict__ src, int ld,
                                  int nwords, int nrows, unsigned* __restrict__ dst) {
    int row  = blockIdx.x;
    int wave = threadIdx.x >> 6, lane = threadIdx.x & 63;
    int nw4  = (nwords + 3) >> 2;
    int wend = (wave + 1) * nw4; if (wend > nwords) wend = nwords;
    const float* r = src + (size_t)row * ld;
    for (int w = wave * nw4; w < wend; ++w) {
        u64 m = __ballot(r[(w << 6) + lane] < 0.0f);
        if (lane < 8) {
            unsigned d = nib8((unsigned)(m >> (8 * lane)) & 0xFFu);
            dst[((size_t)(2 * w + (lane >> 2)) * nrows + row) * 4 + (lane & 3)] = d;
        }
    }
}

// ---------------------------------------------------------------------------
// bit-planes [64][BATCH] (u64) -> fp4 nibble planes [128][BATCH] (16B chunks).
// One thread per (word, row); fully coalesced 16B stores.
// ---------------------------------------------------------------------------
__global__ void expand_bits_kernel(const u64* __restrict__ src,
                                   v4i* __restrict__ dst) {
    int t = blockIdx.x * blockDim.x + threadIdx.x;
    if (t >= 64 * BATCH) return;
    int w = t >> 14, r = t & (BATCH - 1);
    u64 m = src[((size_t)w << 14) + r];
    v4i o0, o1;
    #pragma unroll
    for (int d = 0; d < 4; ++d) {
        o0[d] = (int)nib8((unsigned)(m >> (8 * d)) & 0xFFu);
        o1[d] = (int)nib8((unsigned)(m >> (32 + 8 * d)) & 0xFFu);
    }
    dst[((size_t)(2 * w) << 14) + r]     = o0;
    dst[((size_t)(2 * w + 1) << 14) + r] = o1;
}

// ---------------------------------------------------------------------------
// Binarized GEMM, pure load+MFMA: operands are PRE-EXPANDED fp4 nibble planes
// (scale = 1.0, exact +/-1 dot in f32). No expansion VALU in the K-loop.
// Block tile 128x256, 4 waves (2Mx2N), wave tile 64x128 (2x4 of 32x32),
// K-step 64, acc = 128 f32/lane -> 2 waves/SIMD. 1-round register prefetch.
// blockIdx mapping (bn = blk&15) keeps each XCD on 2 W-panels (L2-resident)
// with consecutive block pairs sharing the A slab.
// ---------------------------------------------------------------------------
__global__ __launch_bounds__(256, 2) void bgemm_fp4n(
    const v4i* __restrict__ AN,   // [2*rounds][BATCH] 16B chunks
    int rounds,
    const v4i* __restrict__ WN,   // [2*rounds][HID] 16B chunks
    const float* __restrict__ bias, const float* __restrict__ gam,
    const float* __restrict__ bet,  const float* __restrict__ mu,
    const float* __restrict__ var,
    u64* __restrict__ OT,         // [64][BATCH] bit planes
    u64* __restrict__ ORM)        // [BATCH][64] row-major or nullptr
{
    const int bm = blockIdx.x >> 4, bn = blockIdx.x & 15;
    const int m0 = bm << 7, n0 = bn << 8;
    const int wave = threadIdx.x >> 6, lane = threadIdx.x & 63;
    const int mh = (wave & 1) << 6, nh = (wave >> 1) << 7;
    const int l31 = lane & 31, q = lane >> 5;

    v16f acc[2][4];
    #pragma unroll
    for (int a = 0; a < 2; ++a)
        #pragma unroll
        for (int b = 0; b < 4; ++b)
            #pragma unroll
            for (int k = 0; k < 16; ++k) acc[a][b][k] = 0.0f;

    const v4i* Ap = AN + (size_t)q * BATCH + (m0 + mh + l31);
    const v4i* Bp = WN + (size_t)q * HID  + (n0 + nh + l31);

    union Frag { v8i v; v4i h[2]; };
    v4i z4 = {0, 0, 0, 0};
    Frag fa[2], fb[4];
    #pragma unroll
    for (int t = 0; t < 2; ++t) { fa[t].h[0] = z4; fa[t].h[1] = z4; }
    #pragma unroll
    for (int t = 0; t < 4; ++t) { fb[t].h[0] = z4; fb[t].h[1] = z4; }

    v4i ra[2], rb[4];
    #pragma unroll
    for (int t = 0; t < 2; ++t) ra[t] = Ap[32 * t];
    #pragma unroll
    for (int t = 0; t < 4; ++t) rb[t] = Bp[32 * t];

    const int sc1 = 0x7f7f7f7f;                 // e8m0 127 -> 2^0 scales

    for (int c = 0; c < rounds; ++c) {
        #pragma unroll
        for (int t = 0; t < 2; ++t) fa[t].h[0] = ra[t];
        #pragma unroll
        for (int t = 0; t < 4; ++t) fb[t].h[0] = rb[t];
        if (c + 1 < rounds) {
            Ap += 2 * BATCH; Bp += 2 * HID;
            #pragma unroll
            for (int t = 0; t < 2; ++t) ra[t] = Ap[32 * t];
            #pragma unroll
            for (int t = 0; t < 4; ++t) rb[t] = Bp[32 * t];
        }
        #pragma unroll
        for (int ti = 0; ti < 2; ++ti)
            #pragma unroll
            for (int tj = 0; tj < 4; ++tj)
                acc[ti][tj] = __builtin_amdgcn_mfma_scale_f32_32x32x64_f8f6f4(
                    fa[ti].v, fb[tj].v, acc[ti][tj], 4, 4, 0, sc1, 0, sc1);
    }

    // epilogue: exact dot in acc, reference-order BN, ballot sign-pack
    float scj[4], muj[4], bej[4], bij[4];
    #pragma unroll
    for (int tj = 0; tj < 4; ++tj) {
        int col = n0 + nh + 32 * tj + l31;
        scj[tj] = gam[col] * rsqrtf(var[col] + EPS);
        muj[tj] = mu[col]; bej[tj] = bet[col]; bij[tj] = bias[col];
    }
    const int pn0 = (n0 + nh) >> 6;             // first output bit-plane
    u64* out0 = OT + (size_t)pn0 * BATCH;
    u64* out1 = OT + (size_t)(pn0 + 1) * BATCH;

    #pragma unroll
    for (int ti = 0; ti < 2; ++ti) {
        #pragma unroll
        for (int reg = 0; reg < 16; ++reg) {
            int rbase = (reg & 3) + 8 * (reg >> 2);
            u64 bl[4];
            #pragma unroll
            for (int tj = 0; tj < 4; ++tj) {
                float h = acc[ti][tj][reg] + bij[tj];
                float y = (h - muj[tj]) * scj[tj] + bej[tj];
                bl[tj] = __ballot(y < 0.0f);
            }
            int rA = m0 + mh + 32 * ti + rbase;  // q=0 lanes' row
            u64 w0A = (bl[0] & 0xFFFFFFFFull) | (bl[1] << 32);
            u64 w0B = (bl[0] >> 32) | (bl[1] & 0xFFFFFFFF00000000ull);
            u64 w1A = (bl[2] & 0xFFFFFFFFull) | (bl[3] << 32);
            u64 w1B = (bl[2] >> 32) | (bl[3] & 0xFFFFFFFF00000000ull);
            if (lane == 0) {
                out0[rA] = w0A; out1[rA] = w1A;
                if (ORM) {
                    ORM[(size_t)rA * 64 + pn0]     = w0A;
                    ORM[(size_t)rA * 64 + pn0 + 1] = w1A;
                }
            } else if (lane == 32) {
                out0[rA + 4] = w0B; out1[rA + 4] = w1B;
                if (ORM) {
                    ORM[(size_t)(rA + 4) * 64 + pn0]     = w0B;
                    ORM[(size_t)(rA + 4) * 64 + pn0 + 1] = w1B;
                }
            }
        }
    }
}

// ---------------------------------------------------------------------------
// Final layer: N=10, K=4096 (64 words). One wave per row; exact-int dots,
// BN, log_softmax.
// ---------------------------------------------------------------------------
__global__ void final_layer_kernel(
    const u64* __restrict__ Ap,   // [B][64] row-major
    const u64* __restrict__ Wp,   // [10][64] row-major
    const float* __restrict__ bias, const float* __restrict__ gam,
    const float* __restrict__ bet,  const float* __restrict__ mu,
    const float* __restrict__ var,
    float* __restrict__ out)      // [B][10]
{
    int gt   = blockIdx.x * blockDim.x + threadIdx.x;
    int row  = gt >> 6;
    int lane = gt & 63;
    if (row >= BATCH) return;

    u64 a = Ap[(size_t)row * 64 + lane];
    unsigned p[NOUT];
    #pragma unroll
    for (int j = 0; j < NOUT; ++j)
        p[j] = (unsigned)__popcll(a ^ Wp[j * 64 + lane]);

    #pragma unroll
    for (int j = 0; j < NOUT; ++j) {
        #pragma unroll
        for (int off = 32; off >= 1; off >>= 1)
            p[j] += __shfl_xor(p[j], off, 64);
    }

    float z[NOUT];
    float mx = -1e30f;
    #pragma unroll
    for (int j = 0; j < NOUT; ++j) {
        float hh = (float)(HID - 2 * (int)p[j]) + bias[j];
        float sc = gam[j] * rsqrtf(var[j] + EPS);
        z[j] = (hh - mu[j]) * sc + bet[j];
        mx = fmaxf(mx, z[j]);
    }
    float s = 0.0f;
    #pragma unroll
    for (int j = 0; j < NOUT; ++j) s += expf(z[j] - mx);
    float lse = logf(s) + mx;
    if (lane < NOUT) out[(size_t)row * NOUT + lane] = z[lane] - lse;
}

// ---------------------------------------------------------------------------
extern "C" void kernel_launch(void* const* d_in, const int* in_sizes, int n_in,
                              void* d_out, int out_size, void* d_ws, size_t ws_size,
                              hipStream_t stream) {
    (void)in_sizes; (void)n_in; (void)out_size; (void)ws_size;

    const float* x   = (const float*)d_in[0];
    const float* w1  = (const float*)d_in[1];
    const float* b1  = (const float*)d_in[2];
    const float* g1  = (const float*)d_in[3];
    const float* be1 = (const float*)d_in[4];
    const float* m1  = (const float*)d_in[5];
    const float* v1  = (const float*)d_in[6];
    const float* w2  = (const float*)d_in[7];
    const float* b2  = (const float*)d_in[8];
    const float* g2  = (const float*)d_in[9];
    const float* be2 = (const float*)d_in[10];
    const float* m2  = (const float*)d_in[11];
    const float* v2  = (const float*)d_in[12];
    const float* w3  = (const float*)d_in[13];
    const float* b3  = (const float*)d_in[14];
    const float* g3  = (const float*)d_in[15];
    const float* be3 = (const float*)d_in[16];
    const float* m3  = (const float*)d_in[17];
    const float* v3  = (const float*)d_in[18];
    const float* w4  = (const float*)d_in[19];
    const float* b4  = (const float*)d_in[20];
    const float* g4  = (const float*)d_in[21];
    const float* be4 = (const float*)d_in[22];
    const float* m4  = (const float*)d_in[23];
    const float* v4  = (const float*)d_in[24];

    // workspace layout (bytes), with lifetime-based sharing:
    //   XN    :  6 MB  x nibbles              [24][BATCH] chunks
    //   W1N   :  1.5MB w1 nibbles             [24][HID]
    //   WBN   :  8 MB  w2 then w3 nibbles     [128][HID]
    //   AN    : 32 MB  A2' then A3' nibbles   [128][BATCH]
    //   aBits :  8 MB  a1 then a2 then a3 bit-planes [64][BATCH]
    //   a3RM  :  8 MB  layer-3 bits row-major [BATCH][64]
    //   w4p   :  5 KB
    char* ws = (char*)d_ws;
    unsigned* XN   = (unsigned*)(ws);
    unsigned* W1N  = (unsigned*)(ws + 6291456);
    unsigned* WBN  = (unsigned*)(ws + 7864320);
    v4i*      ANc  = (v4i*)     (ws + 16252928);
    u64*      aBits= (u64*)     (ws + 49807360);
    u64*      a3RM = (u64*)     (ws + 58195968);
    u64*      w4p  = (u64*)     (ws + 66584576);

    // pack weights / input to fp4 nibble planes (memory-bound)
    pack_nib_t_kernel<<<BATCH, 256, 0, stream>>>(x, 784, 12, BATCH, XN);
    pack_nib_t_kernel<<<HID, 256, 0, stream>>>(w1, IND, 12, HID, W1N);
    pack_nib_t_kernel<<<HID, 256, 0, stream>>>(w2, HID, 64, HID, WBN);
    pack_sign_kernel<<<3, 256, 0, stream>>>(w4, HID, 64, NOUT, w4p);

    // layer 1: K=768 (rounds=12)
    bgemm_fp4n<<<2048, 256, 0, stream>>>((const v4i*)XN, 12, (const v4i*)W1N,
                                         b1, g1, be1, m1, v1, aBits, nullptr);
    expand_bits_kernel<<<4096, 256, 0, stream>>>(aBits, ANc);

    // layer 2: K=4096 (rounds=64); aBits overwritten with a2 (a1 consumed)
    bgemm_fp4n<<<2048, 256, 0, stream>>>((const v4i*)ANc, 64, (const v4i*)WBN,
                                         b2, g2, be2, m2, v2, aBits, nullptr);
    // w3 nibbles overwrite w2 (consumed), A3' overwrites A2' (consumed)
    pack_nib_t_kernel<<<HID, 256, 0, stream>>>(w3, HID, 64, HID, WBN);
    expand_bits_kernel<<<4096, 256, 0, stream>>>(aBits, ANc);

    // layer 3
    bgemm_fp4n<<<2048, 256, 0, stream>>>((const v4i*)ANc, 64, (const v4i*)WBN,
                                         b3, g3, be3, m3, v3, aBits, a3RM);

    // layer 4 + log_softmax
    final_layer_kernel<<<BATCH / 4, 256, 0, stream>>>(a3RM, w4p,
                                                      b4, g4, be4, m4, v4,
                                                      (float*)d_out);
}